// Round 12
// baseline (78.056 us; speedup 1.0000x reference)
//
#include <hip/hip_runtime.h>

#define DD 256
#define HH 4
#define RR 8   // rows per batch

typedef unsigned int uint32x2 __attribute__((ext_vector_type(2)));

// starts[g] = lower_bound(bi, g); starts[G] = N   (bi is sorted)
__global__ void starts_kernel(const int* __restrict__ bi, int* __restrict__ starts,
                              int N, int G) {
    int g = blockIdx.x * blockDim.x + threadIdx.x;
    if (g > G) return;
    int lo = 0, hi = N;
    while (lo < hi) { int mid = (lo + hi) >> 1; if (bi[mid] < g) lo = mid + 1; else hi = mid; }
    starts[g] = lo;
}

// Fully VALU-pipe cross-lane sum-to-all (ZERO DS-pipe ops):
// levels 1,2 via DPP quad_perm; 4,8 via DPP row_ror (rotation covers offsets
// {0,4,8,12} -> row-of-16 sum in all 16 lanes); 16,32 via gfx950
// permlane{16,32}_swap BUILTINS (builtin returns both swap halves -> no
// register-aliasing hazard, unlike r10's inline asm).
template <int CTRL>
__device__ __forceinline__ float dpp_add(float v) {
    const int t = __builtin_amdgcn_update_dpp(0, __float_as_int(v), CTRL, 0xF, 0xF, true);
    return v + __int_as_float(t);
}

__device__ __forceinline__ float wave_allsum(float v) {
    v = dpp_add<0xB1>(v);     // quad_perm [1,0,3,2]  (xor 1)
    v = dpp_add<0x4E>(v);     // quad_perm [2,3,0,1]  (xor 2)
    v = dpp_add<0x124>(v);    // row_ror:4
    v = dpp_add<0x128>(v);    // row_ror:8  -> row-of-16 sum in all 16 lanes
    const uint32x2 r16 = __builtin_amdgcn_permlane16_swap(
        __float_as_uint(v), __float_as_uint(v), false, false);
    v = __uint_as_float(r16.x) + __uint_as_float(r16.y);   // 16-level
    const uint32x2 r32 = __builtin_amdgcn_permlane32_swap(
        __float_as_uint(v), __float_as_uint(v), false, false);
    return __uint_as_float(r32.x) + __uint_as_float(r32.y); // 32-level: full 64-lane sum
}

// ONE WAVE per graph. Single x pass, lane = column (coalesced 1KB/instr),
// ZERO LDS, ZERO barriers, ZERO DS-pipe ops. No-max softmax (validated r7-r11).
__global__ __launch_bounds__(256) void fused_vln(
    const float* __restrict__ x, const int* __restrict__ starts,
    const float* __restrict__ W, const float* __restrict__ b,
    const float* __restrict__ temp, float* __restrict__ ews,
    float* __restrict__ xp, float* __restrict__ aw, int N, int G) {

    const int lane = threadIdx.x & 63;
    const int g = (int)((blockIdx.x * (size_t)blockDim.x + threadIdx.x) >> 6);
    if (g >= G) return;

    const int s = starts[g];
    const int e = starts[g + 1];
    const int cnt = e - s;

    if (cnt == 0) {
        ((float4*)xp)[(size_t)g * 64 + lane] = make_float4(0.f, 0.f, 0.f, 0.f);
        return;
    }

    const float4* __restrict__ x4 = (const float4*)x;
    const float4* __restrict__ W4 = (const float4*)W;
    const float4 w0 = W4[lane];            // lane's 4 columns of each head's W
    const float4 w1 = W4[64 + lane];
    const float4 w2 = W4[128 + lane];
    const float4 w3 = W4[192 + lane];
    const float invT = 1.0f / temp[0];
    const float b0 = b[0], b1 = b[1], b2 = b[2], b3 = b[3];

    const int ngrp = (cnt + 63) >> 6;      // almost always 1 (mean cnt ~31)

    float l0 = 0.f, l1 = 0.f, l2 = 0.f, l3 = 0.f;               // wave-uniform denom
    float4 ac0 = make_float4(0.f,0.f,0.f,0.f), ac1 = ac0, ac2 = ac0, ac3 = ac0;
    float4 em = make_float4(0.f, 0.f, 0.f, 0.f);                // my row's e (per group)

    for (int g0 = 0; g0 < cnt; g0 += 64) {
        const int gs = min(64, cnt - g0);
        for (int i = 0; i < gs; i += RR) {
            float4 xv[RR];
            float p0[RR], p1[RR], p2[RR], p3[RR];

            #pragma unroll
            for (int j = 0; j < RR; ++j) {
                const int r = s + g0 + i + j;
                xv[j] = x4[(size_t)(r < e ? r : e - 1) * 64 + lane];   // coalesced
            }
            #pragma unroll
            for (int j = 0; j < RR; ++j) {
                p0[j] = xv[j].x*w0.x + xv[j].y*w0.y + xv[j].z*w0.z + xv[j].w*w0.w;
                p1[j] = xv[j].x*w1.x + xv[j].y*w1.y + xv[j].z*w1.z + xv[j].w*w1.w;
                p2[j] = xv[j].x*w2.x + xv[j].y*w2.y + xv[j].z*w2.z + xv[j].w*w2.w;
                p3[j] = xv[j].x*w3.x + xv[j].y*w3.y + xv[j].z*w3.z + xv[j].w*w3.w;
            }
            // 64-lane sum-to-all, entirely on the VALU pipe
            #pragma unroll
            for (int j = 0; j < RR; ++j) {
                p0[j] = wave_allsum(p0[j]);
                p1[j] = wave_allsum(p1[j]);
                p2[j] = wave_allsum(p2[j]);
                p3[j] = wave_allsum(p3[j]);
            }
            #pragma unroll
            for (int j = 0; j < RR; ++j) {
                if (i + j < gs) {                       // wave-uniform condition
                    const float e0 = __expf((p0[j] + b0) * invT);
                    const float e1 = __expf((p1[j] + b1) * invT);
                    const float e2 = __expf((p2[j] + b2) * invT);
                    const float e3 = __expf((p3[j] + b3) * invT);
                    l0 += e0; l1 += e1; l2 += e2; l3 += e3;
                    ac0.x += e0*xv[j].x; ac0.y += e0*xv[j].y; ac0.z += e0*xv[j].z; ac0.w += e0*xv[j].w;
                    ac1.x += e1*xv[j].x; ac1.y += e1*xv[j].y; ac1.z += e1*xv[j].z; ac1.w += e1*xv[j].w;
                    ac2.x += e2*xv[j].x; ac2.y += e2*xv[j].y; ac2.z += e2*xv[j].z; ac2.w += e2*xv[j].w;
                    ac3.x += e3*xv[j].x; ac3.y += e3*xv[j].y; ac3.z += e3*xv[j].z; ac3.w += e3*xv[j].w;
                    if (i + j == lane)                  // lane keeps its own row's e
                        em = make_float4(e0, e1, e2, e3);
                }
            }
        }
        if (ngrp > 1 && lane < gs)                      // rare: spill e per 64-group
            ((float4*)ews)[s + g0 + lane] = em;
    }

    const float il0 = 1.f/l0, il1 = 1.f/l1, il2 = 1.f/l2, il3 = 1.f/l3;
    float4 out;
    out.x = 0.25f*(ac0.x*il0 + ac1.x*il1 + ac2.x*il2 + ac3.x*il3);
    out.y = 0.25f*(ac0.y*il0 + ac1.y*il1 + ac2.y*il2 + ac3.y*il3);
    out.z = 0.25f*(ac0.z*il0 + ac1.z*il1 + ac2.z*il2 + ac3.z*il3);
    out.w = 0.25f*(ac0.w*il0 + ac1.w*il1 + ac2.w*il2 + ac3.w*il3);
    ((float4*)xp)[(size_t)g * 64 + lane] = out;

    // attention weights [H, N]
    if (ngrp == 1) {
        if (lane < cnt) {                               // straight from registers
            aw[0 * (size_t)N + s + lane] = em.x * il0;
            aw[1 * (size_t)N + s + lane] = em.y * il1;
            aw[2 * (size_t)N + s + lane] = em.z * il2;
            aw[3 * (size_t)N + s + lane] = em.w * il3;
        }
    } else {
        asm volatile("s_waitcnt vmcnt(0)" ::: "memory");   // our ews stores visible
        for (int r = lane; r < cnt; r += 64) {
            const float4 ev = ((const float4*)ews)[s + r];
            aw[0 * (size_t)N + s + r] = ev.x * il0;
            aw[1 * (size_t)N + s + r] = ev.y * il1;
            aw[2 * (size_t)N + s + r] = ev.z * il2;
            aw[3 * (size_t)N + s + r] = ev.w * il3;
        }
    }
}

extern "C" void kernel_launch(void* const* d_in, const int* in_sizes, int n_in,
                              void* d_out, int out_size, void* d_ws, size_t ws_size,
                              hipStream_t stream) {
    const float* x    = (const float*)d_in[0];
    const int*   bi   = (const int*)d_in[1];
    // d_in[2] = num_graphs (derived from out_size)
    const float* W    = (const float*)d_in[3];
    const float* b    = (const float*)d_in[4];
    const float* temp = (const float*)d_in[5];

    const int N = in_sizes[0] / DD;
    const int G = (out_size - HH * N) / DD;

    float* xp = (float*)d_out;                    // [G, D]
    float* aw = (float*)d_out + (size_t)G * DD;   // [H, N]

    float* ews    = (float*)d_ws;                                  // N*H floats (rare spill)
    int*   starts = (int*)((char*)d_ws + (size_t)N * HH * 4);      // G+1 ints

    starts_kernel<<<(G + 1 + 255) / 256, 256, 0, stream>>>(bi, starts, N, G);
    fused_vln<<<(G * 64 + 255) / 256, 256, 0, stream>>>(
        x, starts, W, b, temp, ews, xp, aw, N, G);
}

// Round 13
// 65.240 us; speedup vs baseline: 1.1964x; 1.1964x over previous
//
#include <hip/hip_runtime.h>

#define DD 256
#define HH 4
#define RR 4   // rows per batch (was 8: halves xv/p register arrays -> occupancy up)

// starts[g] = lower_bound(bi, g); starts[G] = N   (bi is sorted)
__global__ void starts_kernel(const int* __restrict__ bi, int* __restrict__ starts,
                              int N, int G) {
    int g = blockIdx.x * blockDim.x + threadIdx.x;
    if (g > G) return;
    int lo = 0, hi = N;
    while (lo < hi) { int mid = (lo + hi) >> 1; if (bi[mid] < g) lo = mid + 1; else hi = mid; }
    starts[g] = lo;
}

// Hybrid cross-lane sum-to-all (r11-proven, pipe-balanced): levels 1,2,4,8 on the
// VALU pipe via DPP; levels 16,32 via __shfl_xor (2 DS ops). r12 proved moving
// those last 2 levels to VALU permlane regresses (+5.3us) - pipes now balanced.
template <int CTRL>
__device__ __forceinline__ float dpp_add(float v) {
    const int t = __builtin_amdgcn_update_dpp(0, __float_as_int(v), CTRL, 0xF, 0xF, true);
    return v + __int_as_float(t);
}

__device__ __forceinline__ float wave_allsum(float v) {
    v = dpp_add<0xB1>(v);     // quad_perm [1,0,3,2]  (xor 1)
    v = dpp_add<0x4E>(v);     // quad_perm [2,3,0,1]  (xor 2)
    v = dpp_add<0x124>(v);    // row_ror:4
    v = dpp_add<0x128>(v);    // row_ror:8  -> row-of-16 sum in all 16 lanes
    v += __shfl_xor(v, 16);
    v += __shfl_xor(v, 32);
    return v;                 // full 64-lane sum in every lane
}

// ONE WAVE per graph. Single x pass, lane = column (coalesced 1KB/instr),
// ZERO LDS, ZERO barriers, 2 DS ops per reduction. No-max softmax (validated r7-r12).
__global__ __launch_bounds__(256) void fused_hyb4(
    const float* __restrict__ x, const int* __restrict__ starts,
    const float* __restrict__ W, const float* __restrict__ b,
    const float* __restrict__ temp, float* __restrict__ ews,
    float* __restrict__ xp, float* __restrict__ aw, int N, int G) {

    const int lane = threadIdx.x & 63;
    const int g = (int)((blockIdx.x * (size_t)blockDim.x + threadIdx.x) >> 6);
    if (g >= G) return;

    const int s = starts[g];
    const int e = starts[g + 1];
    const int cnt = e - s;

    if (cnt == 0) {
        ((float4*)xp)[(size_t)g * 64 + lane] = make_float4(0.f, 0.f, 0.f, 0.f);
        return;
    }

    const float4* __restrict__ x4 = (const float4*)x;
    const float4* __restrict__ W4 = (const float4*)W;
    const float4 w0 = W4[lane];            // lane's 4 columns of each head's W
    const float4 w1 = W4[64 + lane];
    const float4 w2 = W4[128 + lane];
    const float4 w3 = W4[192 + lane];
    const float invT = 1.0f / temp[0];
    const float b0 = b[0], b1 = b[1], b2 = b[2], b3 = b[3];

    const int ngrp = (cnt + 63) >> 6;      // almost always 1 (mean cnt ~31)

    float l0 = 0.f, l1 = 0.f, l2 = 0.f, l3 = 0.f;               // wave-uniform denom
    float4 ac0 = make_float4(0.f,0.f,0.f,0.f), ac1 = ac0, ac2 = ac0, ac3 = ac0;
    float4 em = make_float4(0.f, 0.f, 0.f, 0.f);                // my row's e (per group)

    for (int g0 = 0; g0 < cnt; g0 += 64) {
        const int gs = min(64, cnt - g0);
        for (int i = 0; i < gs; i += RR) {
            float4 xv[RR];
            float p0[RR], p1[RR], p2[RR], p3[RR];

            #pragma unroll
            for (int j = 0; j < RR; ++j) {
                const int r = s + g0 + i + j;
                xv[j] = x4[(size_t)(r < e ? r : e - 1) * 64 + lane];   // coalesced
            }
            #pragma unroll
            for (int j = 0; j < RR; ++j) {
                p0[j] = xv[j].x*w0.x + xv[j].y*w0.y + xv[j].z*w0.z + xv[j].w*w0.w;
                p1[j] = xv[j].x*w1.x + xv[j].y*w1.y + xv[j].z*w1.z + xv[j].w*w1.w;
                p2[j] = xv[j].x*w2.x + xv[j].y*w2.y + xv[j].z*w2.z + xv[j].w*w2.w;
                p3[j] = xv[j].x*w3.x + xv[j].y*w3.y + xv[j].z*w3.z + xv[j].w*w3.w;
            }
            // 64-lane sum-to-all: 4 DPP levels (VALU) + 2 shfl levels (DS)
            #pragma unroll
            for (int j = 0; j < RR; ++j) {
                p0[j] = wave_allsum(p0[j]);
                p1[j] = wave_allsum(p1[j]);
                p2[j] = wave_allsum(p2[j]);
                p3[j] = wave_allsum(p3[j]);
            }
            #pragma unroll
            for (int j = 0; j < RR; ++j) {
                if (i + j < gs) {                       // wave-uniform condition
                    const float e0 = __expf((p0[j] + b0) * invT);
                    const float e1 = __expf((p1[j] + b1) * invT);
                    const float e2 = __expf((p2[j] + b2) * invT);
                    const float e3 = __expf((p3[j] + b3) * invT);
                    l0 += e0; l1 += e1; l2 += e2; l3 += e3;
                    ac0.x += e0*xv[j].x; ac0.y += e0*xv[j].y; ac0.z += e0*xv[j].z; ac0.w += e0*xv[j].w;
                    ac1.x += e1*xv[j].x; ac1.y += e1*xv[j].y; ac1.z += e1*xv[j].z; ac1.w += e1*xv[j].w;
                    ac2.x += e2*xv[j].x; ac2.y += e2*xv[j].y; ac2.z += e2*xv[j].z; ac2.w += e2*xv[j].w;
                    ac3.x += e3*xv[j].x; ac3.y += e3*xv[j].y; ac3.z += e3*xv[j].z; ac3.w += e3*xv[j].w;
                    if (i + j == lane)                  // lane keeps its own row's e
                        em = make_float4(e0, e1, e2, e3);
                }
            }
        }
        if (ngrp > 1 && lane < gs)                      // rare: spill e per 64-group
            ((float4*)ews)[s + g0 + lane] = em;
    }

    const float il0 = 1.f/l0, il1 = 1.f/l1, il2 = 1.f/l2, il3 = 1.f/l3;
    float4 out;
    out.x = 0.25f*(ac0.x*il0 + ac1.x*il1 + ac2.x*il2 + ac3.x*il3);
    out.y = 0.25f*(ac0.y*il0 + ac1.y*il1 + ac2.y*il2 + ac3.y*il3);
    out.z = 0.25f*(ac0.z*il0 + ac1.z*il1 + ac2.z*il2 + ac3.z*il3);
    out.w = 0.25f*(ac0.w*il0 + ac1.w*il1 + ac2.w*il2 + ac3.w*il3);
    ((float4*)xp)[(size_t)g * 64 + lane] = out;

    // attention weights [H, N]
    if (ngrp == 1) {
        if (lane < cnt) {                               // straight from registers
            aw[0 * (size_t)N + s + lane] = em.x * il0;
            aw[1 * (size_t)N + s + lane] = em.y * il1;
            aw[2 * (size_t)N + s + lane] = em.z * il2;
            aw[3 * (size_t)N + s + lane] = em.w * il3;
        }
    } else {
        asm volatile("s_waitcnt vmcnt(0)" ::: "memory");   // our ews stores visible
        for (int r = lane; r < cnt; r += 64) {
            const float4 ev = ((const float4*)ews)[s + r];
            aw[0 * (size_t)N + s + r] = ev.x * il0;
            aw[1 * (size_t)N + s + r] = ev.y * il1;
            aw[2 * (size_t)N + s + r] = ev.z * il2;
            aw[3 * (size_t)N + s + r] = ev.w * il3;
        }
    }
}

extern "C" void kernel_launch(void* const* d_in, const int* in_sizes, int n_in,
                              void* d_out, int out_size, void* d_ws, size_t ws_size,
                              hipStream_t stream) {
    const float* x    = (const float*)d_in[0];
    const int*   bi   = (const int*)d_in[1];
    // d_in[2] = num_graphs (derived from out_size)
    const float* W    = (const float*)d_in[3];
    const float* b    = (const float*)d_in[4];
    const float* temp = (const float*)d_in[5];

    const int N = in_sizes[0] / DD;
    const int G = (out_size - HH * N) / DD;

    float* xp = (float*)d_out;                    // [G, D]
    float* aw = (float*)d_out + (size_t)G * DD;   // [H, N]

    float* ews    = (float*)d_ws;                                  // N*H floats (rare spill)
    int*   starts = (int*)((char*)d_ws + (size_t)N * HH * 4);      // G+1 ints

    starts_kernel<<<(G + 1 + 255) / 256, 256, 0, stream>>>(bi, starts, N, G);
    fused_hyb4<<<(G * 64 + 255) / 256, 256, 0, stream>>>(
        x, starts, W, b, temp, ews, xp, aw, N, G);
}